// Round 18
// baseline (77.565 us; speedup 1.0000x reference)
//
#include <hip/hip_runtime.h>

// Fully-MFMA fused model: gates (LSTM heads) AND the 4-layer MLP all run on
// the matrix pipe in swapped-operand form (A = weights, B = samples^T).
//   gate layer: W_aug[112x34] = unit-major (i,g,o,pad) rows for 22 units +
//               12 identity copy-rows for passthrough features + pad.
//               Nonlinearity is lane-local (unit's i,g,o in one acc f4).
//   handoff gate->L1 via phi map (h-units {4jj+g} + group-g copies), packed
//   in-register; L1..L4 use the pi k-permutation (r16-verified).
// stage0 stages RAW x pairs; the only LDS round-trip is x staging.
// Bias rides ks=0 MFMA C (per-row fragments). Two 32-sample halves per wave
// bound VGPR. Per-wave epilogue (no barrier), coalesced 320-float store.

#define BLK  256
#define WPB  4

#define N_FRAG_U32 (38 * 256)   // 14 gate + 8 L1 + 8 L2 + 6 L3 + 2 L4 tiles
#define N_BIAS     (19 * 256)   // 12 MLP + 7 gate bias tiles (f32)

#define TB_G  0
#define TB_L1 14
#define TB_L2 22
#define TB_L3 30
#define TB_L4 36
#define BB_L1 0
#define BB_L2 4
#define BB_L3 8
#define BB_L4 11
#define BB_G  12

typedef _Float16 h2 __attribute__((ext_vector_type(2)));
typedef _Float16 h8 __attribute__((ext_vector_type(8)));
typedef float    f4 __attribute__((ext_vector_type(4)));

struct __attribute__((packed, aligned(8))) pf4 { f4 v; };

__device__ __align__(16) unsigned g_frag[N_FRAG_U32];
__device__ __align__(16) float    g_bias[N_BIAS];

__device__ __forceinline__ h2 pk(float a, float b) {
    auto r = __builtin_amdgcn_cvt_pkrtz(a, b);
    union { decltype(r) f; h2 h; } c; c.f = r; return c.h;
}
__device__ __forceinline__ unsigned as_u32(h2 h) {
    union { h2 h; unsigned u; } c; c.h = h; return c.u;
}
__device__ __forceinline__ float uf(unsigned u) {
    union { unsigned u; float f; } c; c.u = u; return c.f;
}
__device__ __forceinline__ unsigned pkrelu(float a, float b) {
    h2 p = pk(a, b);
    h2 z = {(_Float16)0.0f, (_Float16)0.0f};
    h2 r = __builtin_elementwise_max(p, z);
    return as_u32(r);
}
__device__ __forceinline__ float fast_exp(float x) {
#if __has_builtin(__builtin_amdgcn_exp2f)
    return __builtin_amdgcn_exp2f(x * 1.44269504088896340736f);
#else
    return __expf(x);
#endif
}
__device__ __forceinline__ float fast_rcp(float x) {
#if __has_builtin(__builtin_amdgcn_rcpf)
    return __builtin_amdgcn_rcpf(x);
#else
    return 1.0f / x;
#endif
}
__device__ __forceinline__ float sig1(float x) { return fast_rcp(1.0f + fast_exp(-x)); }
// sig(a)*tanh(b) with one rcp
__device__ __forceinline__ float sigtanh(float a, float b) {
    float ea = fast_exp(-a);
    float eb = fast_exp(2.0f * b);
    return (eb - 1.0f) * fast_rcp((1.0f + ea) * (eb + 1.0f));
}

// ---------- prep maps ----------
// pi: k-position -> feature for L2/L3/L4 (in-register relu-pack order)
__device__ __forceinline__ int pi_map(int q) {
    return (2 * (q >> 5) + ((q & 7) >> 2)) * 16 + ((q >> 3) & 3) * 4 + (q & 3);
}
// phi: k-position -> cat feature for L1 (gate-output pack order); -1 = zero
__device__ __forceinline__ int phi_map(int q) {
    int ksq = q >> 5, rem = q & 31, gq = rem >> 3, jj = rem & 7;
    if (ksq == 0) {
        if (jj < 6) { int u = 4 * jj + gq; return (u < 22) ? u : -1; }
        return (gq < 3) ? (22 + 4 * gq + (jj - 6)) : -1;
    }
    if (jj < 2 && gq < 3) return 24 + 4 * gq + jj;
    return -1;
}
// augmented gate matrix W_aug[112][34]: rows 4u+{0,1,2} = (i,g,o) of unit u
// (unit u = 2k+jg), rows 96+cf = identity copy of feature 22+cf, else 0.
__device__ __forceinline__ float waug(int row, int feat, const float* W_ih) {
    if (feat >= 34) return 0.f;
    if (row >= 96) { int cf = row - 96; return (cf < 12 && feat == 22 + cf) ? 1.f : 0.f; }
    int u = row >> 2, r = row & 3;
    if (u >= 22 || r == 3) return 0.f;
    int k = u >> 1, jg = u & 1;
    if ((feat >> 1) != k) return 0.f;
    int h = feat & 1;
    int g8 = (r == 0) ? jg : (r == 1) ? 4 + jg : 6 + jg;
    return W_ih[k * 16 + g8 * 2 + h];
}
__device__ __forceinline__ float baug(int row, const float* b_ih, const float* b_hh) {
    if (row >= 96) return 0.f;
    int u = row >> 2, r = row & 3;
    if (u >= 22 || r == 3) return 0.f;
    int k = u >> 1, jg = u & 1;
    int g8 = (r == 0) ? jg : (r == 1) ? 4 + jg : 6 + jg;
    return b_ih[k * 8 + g8] + b_hh[k * 8 + g8];
}

__global__ void prep_weights(const float* __restrict__ W_ih, const float* __restrict__ b_ih,
                             const float* __restrict__ b_hh,
                             const float* __restrict__ W1, const float* __restrict__ b1,
                             const float* __restrict__ W2, const float* __restrict__ b2,
                             const float* __restrict__ W3, const float* __restrict__ b3,
                             const float* __restrict__ W4, const float* __restrict__ b4)
{
    const int gid = blockIdx.x * blockDim.x + threadIdx.x;
    const int gs  = gridDim.x * blockDim.x;

    for (int i = gid; i < N_FRAG_U32; i += gs) {
        int t = i >> 8, rlo = i & 255;
        int lane = rlo >> 2, j = rlo & 3;
        float a, b;
        if (t < TB_L1) {                                   // gate tiles (ks*7+ot)
            int ks = t / 7, ot = t - ks * 7;
            int row = ot * 16 + (lane & 15);
            int p = ks * 16 + (lane >> 4) * 4 + j;
            a = waug(row, 2 * p,     W_ih);
            b = waug(row, 2 * p + 1, W_ih);
        } else {
            const float* W; int N, K, ld, ks, nt, usephi;
            if (t < TB_L2)      { W = W1; N = 51; K = 34; ld = 34; int tt = t - TB_L1; ks = tt >> 2; nt = tt & 3; usephi = 1; }
            else if (t < TB_L3) { W = W2; N = 51; K = 51; ld = 51; int tt = t - TB_L2; ks = tt >> 2; nt = tt & 3; usephi = 0; }
            else if (t < TB_L4) { W = W3; N = 34; K = 51; ld = 51; int tt = t - TB_L3; ks = tt / 3; nt = tt - 3 * ks; usephi = 0; }
            else                { W = W4; N = 5;  K = 34; ld = 34; ks = t - TB_L4; nt = 0; usephi = 0; }
            int m  = nt * 16 + (lane & 15);
            int q0 = ks * 32 + (lane >> 4) * 8 + 2 * j;
            int f0, f1;
            if (usephi) { f0 = phi_map(q0); f1 = phi_map(q0 + 1); }
            else {
                f0 = pi_map(q0);     if (f0 >= K) f0 = -1;
                f1 = pi_map(q0 + 1); if (f1 >= K) f1 = -1;
            }
            a = (m < N && f0 >= 0) ? W[m * ld + f0] : 0.f;
            b = (m < N && f1 >= 0) ? W[m * ld + f1] : 0.f;
        }
        g_frag[i] = as_u32(pk(a, b));
    }

    for (int i = gid; i < N_BIAS; i += gs) {
        int bt = i >> 8, rem = i & 255;
        int lane = rem >> 2, r = rem & 3;
        int rowloc = (lane >> 4) * 4 + r;
        float v;
        if (bt < BB_G) {
            const float* bv; int N, ot;
            if (bt < 4)       { bv = b1; N = 51; ot = bt; }
            else if (bt < 8)  { bv = b2; N = 51; ot = bt - 4; }
            else if (bt < 11) { bv = b3; N = 34; ot = bt - 8; }
            else              { bv = b4; N = 5;  ot = 0; }
            int n = ot * 16 + rowloc;
            v = (n < N) ? bv[n] : 0.f;
        } else {
            int row = (bt - BB_G) * 16 + rowloc;
            v = baug(row, b_ih, b_hh);
        }
        g_bias[i] = v;
    }
}

// ---------- main kernel helpers ----------
__device__ __forceinline__ h8 load_frag(int tile, int l) {
    union { uint4 u; h8 h; } u;
    u.u = *(const uint4*)&g_frag[tile * 256 + l * 4];
    return u.h;
}

// B-frags for 2 sample-tiles of the given half from the x stage0 tile
__device__ __forceinline__ void read_bfrags2(h8 (&bf)[2][2], const unsigned* my, int l, int half) {
    const int c = l & 15, g = l >> 4;
    const int mrd = (c & 7) << 2;
    #pragma unroll
    for (int st = 0; st < 2; ++st)
      #pragma unroll
      for (int ks = 0; ks < 2; ++ks) {
        int idx = ((half * 2 + st) * 16 + c) * 32 + ((ks * 16 + g * 4) ^ mrd);
        union { uint4 u; h8 h; } u;
        u.u = *(const uint4*)&my[idx];
        bf[st][ks] = u.h;
      }
}

// gate layer: acc[7][2], bias from gate bias tiles
__device__ __forceinline__ void layer_gates(const h8 (&bf)[2][2], f4 (&acc)[7][2], int l) {
    #pragma unroll
    for (int ot = 0; ot < 7; ++ot) {
        f4 bias4 = *(const f4*)&g_bias[(BB_G + ot) * 256 + l * 4];
        h8 af = load_frag(TB_G + ot, l);
        acc[ot][0] = __builtin_amdgcn_mfma_f32_16x16x32_f16(af, bf[0][0], bias4, 0, 0, 0);
        acc[ot][1] = __builtin_amdgcn_mfma_f32_16x16x32_f16(af, bf[1][0], bias4, 0, 0, 0);
    }
    #pragma unroll
    for (int ot = 0; ot < 7; ++ot) {
        h8 af = load_frag(TB_G + 7 + ot, l);
        acc[ot][0] = __builtin_amdgcn_mfma_f32_16x16x32_f16(af, bf[0][1], acc[ot][0], 0, 0, 0);
        acc[ot][1] = __builtin_amdgcn_mfma_f32_16x16x32_f16(af, bf[1][1], acc[ot][1], 0, 0, 0);
    }
}

// nonlinearity + L1 B-frag pack (phi order): slot jj<6 = h(unit 4jj+g),
// slots 6,7 / ks1 0,1 = copy features (tile 6, raw). Pad units self-zero.
__device__ __forceinline__ void gates_to_bf(const f4 (&acc)[7][2], h8 (&bf)[2][2]) {
    #pragma unroll
    for (int st = 0; st < 2; ++st) {
        float h[6];
        #pragma unroll
        for (int ot = 0; ot < 6; ++ot) {
            float cc = sigtanh(acc[ot][st][0], acc[ot][st][1]);   // sig(i)*tanh(g)
            h[ot]    = sigtanh(acc[ot][st][2], cc);               // sig(o)*tanh(cc)
        }
        union { unsigned u[4]; h8 hh; } c0, c1;
        c0.u[0] = as_u32(pk(h[0], h[1]));
        c0.u[1] = as_u32(pk(h[2], h[3]));
        c0.u[2] = as_u32(pk(h[4], h[5]));
        c0.u[3] = as_u32(pk(acc[6][st][0], acc[6][st][1]));       // copies, raw
        c1.u[0] = as_u32(pk(acc[6][st][2], acc[6][st][3]));
        c1.u[1] = 0u; c1.u[2] = 0u; c1.u[3] = 0u;
        bf[st][0] = c0.hh; bf[st][1] = c1.hh;
    }
}

template<int NT, int TBASE, int BBASE>
__device__ __forceinline__ void layerN(const h8 (&bf)[2][2], f4 (&acc)[4][2], int l) {
    #pragma unroll
    for (int ot = 0; ot < NT; ++ot) {
        f4 bias4 = *(const f4*)&g_bias[(BBASE + ot) * 256 + l * 4];
        h8 af = load_frag(TBASE + ot, l);
        acc[ot][0] = __builtin_amdgcn_mfma_f32_16x16x32_f16(af, bf[0][0], bias4, 0, 0, 0);
        acc[ot][1] = __builtin_amdgcn_mfma_f32_16x16x32_f16(af, bf[1][0], bias4, 0, 0, 0);
    }
    #pragma unroll
    for (int ot = 0; ot < NT; ++ot) {
        h8 af = load_frag(TBASE + NT + ot, l);
        acc[ot][0] = __builtin_amdgcn_mfma_f32_16x16x32_f16(af, bf[0][1], acc[ot][0], 0, 0, 0);
        acc[ot][1] = __builtin_amdgcn_mfma_f32_16x16x32_f16(af, bf[1][1], acc[ot][1], 0, 0, 0);
    }
}

// relu + pack under pi (r16-verified), ST=2
template<int NT>
__device__ __forceinline__ void pack_bfrags2(const f4 (&acc)[4][2], h8 (&bf)[2][2]) {
    #pragma unroll
    for (int st = 0; st < 2; ++st)
      #pragma unroll
      for (int ks = 0; ks < 2; ++ks) {
        const int o0 = 2 * ks, o1 = 2 * ks + 1;
        union { unsigned u[4]; h8 h; } cvt;
        cvt.u[0] = pkrelu(acc[o0][st][0], acc[o0][st][1]);
        cvt.u[1] = pkrelu(acc[o0][st][2], acc[o0][st][3]);
        if (o1 < NT) {
            cvt.u[2] = pkrelu(acc[o1][st][0], acc[o1][st][1]);
            cvt.u[3] = pkrelu(acc[o1][st][2], acc[o1][st][3]);
        } else {
            cvt.u[2] = 0u; cvt.u[3] = 0u;
        }
        bf[st][ks] = cvt.h;
      }
}

// stage0: write raw-x pair row (row = l), swizzled
__device__ __forceinline__ void stage0(const unsigned (&cp)[32], unsigned* my, int l) {
    const int m = (l & 7) << 2;
    #pragma unroll
    for (int ch = 0; ch < 8; ++ch) {
        uint4 q = make_uint4(cp[4*ch], cp[4*ch+1], cp[4*ch+2], cp[4*ch+3]);
        *(uint4*)&my[l * 32 + ((4 * ch) ^ m)] = q;
    }
}

__global__ __launch_bounds__(BLK, 3)
void fused_rnn_mlp(const float* __restrict__ in, float* __restrict__ out, int nrows)
{
    __shared__ unsigned act[WPB * 2048];                 // 8 KB per wave-slice
    const int tid = threadIdx.x;
    const int w = tid >> 6, l = tid & 63;
    unsigned* my = &act[w * 2048];
    const long long rb = (long long)blockIdx.x * BLK;
    if (rb + BLK > nrows) return;
    const long long rw = rb + w * 64;

    // own row: 8 x dwordx4 + 1 x dwordx2 -> raw fp16 pairs
    unsigned cp[32];
    {
        const float* rp = in + (rw + l) * 34;
        #pragma unroll
        for (int q = 0; q < 8; ++q) {
            f4 v = ((const pf4*)(rp))[q].v;
            cp[2 * q]     = as_u32(pk(v.x, v.y));
            cp[2 * q + 1] = as_u32(pk(v.z, v.w));
        }
        float2 t = *(const float2*)(rp + 32);
        cp[16] = as_u32(pk(t.x, t.y));
        #pragma unroll
        for (int t2 = 17; t2 < 32; ++t2) cp[t2] = 0u;
    }
    stage0(cp, my, l);

    f4 outh[2][2];                                       // [half][st], static idx

    #pragma unroll
    for (int half = 0; half < 2; ++half) {
        h8 bf[2][2];
        read_bfrags2(bf, my, l, half);

        f4 accg[7][2];
        layer_gates(bf, accg, l);                        // gates+copies: 34 -> 112
        gates_to_bf(accg, bf);                           // lane-local nonlin + pack

        f4 acc[4][2];
        layerN<4, TB_L1, BB_L1>(bf, acc, l);             // L1: 34(cat) -> 51
        pack_bfrags2<4>(acc, bf);
        layerN<4, TB_L2, BB_L2>(bf, acc, l);             // L2: 51 -> 51
        pack_bfrags2<4>(acc, bf);
        layerN<3, TB_L3, BB_L3>(bf, acc, l);             // L3: 51 -> 34
        pack_bfrags2<3>(acc, bf);
        layerN<1, TB_L4, BB_L4>(bf, acc, l);             // L4: 34 -> 5
        outh[half][0] = acc[0][0];
        outh[half][1] = acc[0][1];
    }

    // stage PRE-sigmoid f32 (lane holds neurons g*4+r of sample hs*16+c)
    {
        const int c = l & 15, g = l >> 4;
        float* po = (float*)my;
        #pragma unroll
        for (int hs = 0; hs < 4; ++hs) {
            const int sample = hs * 16 + c;
            #pragma unroll
            for (int r = 0; r < 4; ++r) {
                int n = g * 4 + r;
                if (n < 5) po[sample * 9 + n] = outh[hs >> 1][hs & 1][r];
            }
        }
    }
    // per-wave coalesced store (same-wave LDS RAW; no barrier)
    {
        const float* po = (const float*)my;
        const long long ob = rw * 5;
        #pragma unroll
        for (int it = 0; it < 5; ++it) {
            int F   = it * 64 + l;
            int row = (F * 52429) >> 18;                 // F / 5, exact
            int cc  = F - row * 5;
            out[ob + F] = sig1(po[row * 9 + cc]);
        }
    }
}

extern "C" void kernel_launch(void* const* d_in, const int* in_sizes, int n_in,
                              void* d_out, int out_size, void* d_ws, size_t ws_size,
                              hipStream_t stream)
{
    const float* input = (const float*)d_in[0];
    const float* W_ih  = (const float*)d_in[1];
    const float* b_ih  = (const float*)d_in[2];
    const float* b_hh  = (const float*)d_in[3];
    const float* W1    = (const float*)d_in[4];
    const float* b1    = (const float*)d_in[5];
    const float* W2    = (const float*)d_in[6];
    const float* b2    = (const float*)d_in[7];
    const float* W3    = (const float*)d_in[8];
    const float* b3    = (const float*)d_in[9];
    const float* W4    = (const float*)d_in[10];
    const float* b4    = (const float*)d_in[11];
    float* out = (float*)d_out;

    int nrows = in_sizes[0] / 34;
    int grid  = nrows / BLK;

    hipLaunchKernelGGL(prep_weights, dim3(8), dim3(256), 0, stream,
                       W_ih, b_ih, b_hh, W1, b1, W2, b2, W3, b3, W4, b4);
    hipLaunchKernelGGL(fused_rnn_mlp, dim3(grid), dim3(BLK), 0, stream,
                       input, out, nrows);
}

// Round 19
// 57.200 us; speedup vs baseline: 1.3560x; 1.3560x over previous
//
#include <hip/hip_runtime.h>

// Fused LSTM-heads + 4-layer MLP on the MATRIX pipe — SWAPPED-OPERAND form.
// Each layer computes D' = W · act^T  (A = W, B = activations^T); with the
// pi k-permutation applied to BOTH packed activations and next-layer W
// columns, the inter-layer handoff is PURE IN-REGISTER (8 pkrelu/sample-tile).
// Only L1 reads B-frags from the stage0 LDS tile. Bias rides ks=0 MFMA C.
// r17: input as 8 x dwordx4 + 1 x dwordx2; per-wave barrier-free epilogue.
// r19: __launch_bounds__(256,4) — cap VGPR at 128 to lift occupancy from
//      3 to 4 waves/SIMD (r12 evidence: occupancy was VGPR-capped at 3).

#define BLK  256
#define WPB  4
#define KSEQ 11

typedef _Float16 h2   __attribute__((ext_vector_type(2)));
typedef _Float16 h8   __attribute__((ext_vector_type(8)));
typedef float    f4   __attribute__((ext_vector_type(4)));
typedef unsigned u16v __attribute__((ext_vector_type(16)));

struct __attribute__((packed, aligned(8))) pf4 { f4 v; };   // align-8 float4 load

#define N_FRAG_U32 6144   // 24 tiles * 64 lanes * 4 u32 (f16 pairs)
#define N_BIAS     3072   // 12 bias-tiles * 64 lanes * 4 rows (f32)
#define N_LSTM     288    // 12 * 24 floats (W_ih 16 + folded bias 8 per k)

__device__ __align__(16) float    g_lstm[N_LSTM];
__device__ __align__(16) unsigned g_frag[N_FRAG_U32];
__device__ __align__(16) float    g_bias[N_BIAS];

__device__ __forceinline__ h2 pk(float a, float b) {
    auto r = __builtin_amdgcn_cvt_pkrtz(a, b);
    union { decltype(r) f; h2 h; } c; c.f = r; return c.h;
}
__device__ __forceinline__ unsigned as_u32(h2 h) {
    union { h2 h; unsigned u; } c; c.h = h; return c.u;
}
__device__ __forceinline__ float uf(unsigned u) {
    union { unsigned u; float f; } c; c.u = u; return c.f;
}
__device__ __forceinline__ unsigned pkrelu(float a, float b) {   // pack then v_pk_max_f16
    h2 p = pk(a, b);
    h2 z = {(_Float16)0.0f, (_Float16)0.0f};
    h2 r = __builtin_elementwise_max(p, z);
    return as_u32(r);
}
__device__ __forceinline__ float fast_exp(float x) {
#if __has_builtin(__builtin_amdgcn_exp2f)
    return __builtin_amdgcn_exp2f(x * 1.44269504088896340736f);
#else
    return __expf(x);
#endif
}
__device__ __forceinline__ float fast_rcp(float x) {
#if __has_builtin(__builtin_amdgcn_rcpf)
    return __builtin_amdgcn_rcpf(x);
#else
    return 1.0f / x;
#endif
}
__device__ __forceinline__ float sig1(float x)  { return fast_rcp(1.0f + fast_exp(-x)); }

// sig(a) * tanh(b) with a single rcp
__device__ __forceinline__ float sigtanh(float a, float b) {
    float ea = fast_exp(-a);
    float eb = fast_exp(2.0f * b);
    return (eb - 1.0f) * fast_rcp((1.0f + ea) * (eb + 1.0f));
}

// scalar-pipe load of 48 u32 (LSTM params for a k-pair); waitcnt fused in-block
__device__ __forceinline__ void sload3(const unsigned* p, u16v& c0, u16v& c1, u16v& c2) {
    asm volatile("s_load_dwordx16 %0, %3, 0x0\n\t"
                 "s_load_dwordx16 %1, %3, 0x40\n\t"
                 "s_load_dwordx16 %2, %3, 0x80\n\t"
                 "s_waitcnt lgkmcnt(0)"
                 : "=&s"(c0), "=&s"(c1), "=&s"(c2) : "s"(p));
}
__device__ __forceinline__ unsigned pick48(const u16v& c0, const u16v& c1, const u16v& c2, int j) {
    return j < 16 ? c0[j] : (j < 32 ? c1[j - 16] : c2[j - 32]);
}

__device__ __forceinline__ void lstm_one(const u16v& c0, const u16v& c1, const u16v& c2, int base,
                                         float2 x, h2& outp)
{
    float w0  = uf(pick48(c0, c1, c2, base + 0)),  w1  = uf(pick48(c0, c1, c2, base + 1));
    float w2  = uf(pick48(c0, c1, c2, base + 2)),  w3  = uf(pick48(c0, c1, c2, base + 3));
    float w8  = uf(pick48(c0, c1, c2, base + 8)),  w9  = uf(pick48(c0, c1, c2, base + 9));
    float w10 = uf(pick48(c0, c1, c2, base + 10)), w11 = uf(pick48(c0, c1, c2, base + 11));
    float w12 = uf(pick48(c0, c1, c2, base + 12)), w13 = uf(pick48(c0, c1, c2, base + 13));
    float w14 = uf(pick48(c0, c1, c2, base + 14)), w15 = uf(pick48(c0, c1, c2, base + 15));
    float B0  = uf(pick48(c0, c1, c2, base + 16)), B1v = uf(pick48(c0, c1, c2, base + 17));
    float B4  = uf(pick48(c0, c1, c2, base + 20)), B5  = uf(pick48(c0, c1, c2, base + 21));
    float B6  = uf(pick48(c0, c1, c2, base + 22)), B7  = uf(pick48(c0, c1, c2, base + 23));

    float x0 = x.x, x1 = x.y;
    float gi0 = B0  + x0 * w0  + x1 * w1;
    float gi1 = B1v + x0 * w2  + x1 * w3;
    float gg0 = B4  + x0 * w8  + x1 * w9;
    float gg1 = B5  + x0 * w10 + x1 * w11;
    float go0 = B6  + x0 * w12 + x1 * w13;
    float go1 = B7  + x0 * w14 + x1 * w15;
    float cc0 = sigtanh(gi0, gg0);
    float cc1 = sigtanh(gi1, gg1);
    float h0  = sigtanh(go0, cc0);
    float h1  = sigtanh(go1, cc1);
    outp = pk(h0, h1);
}

// ---- prep: pack W as A-fragments, per-ROW bias tiles, LSTM params ----
// tile ids: L1: 0..7 = ks*4+nt | L2: 8..15 | L3: 16..21 = 16+ks*3+nt | L4: 22..23
// A-frag: lane holds W[m = nt*16+(lane&15)][k-position (lane>>4)*8 + jj of step ks].
//   L1 (stage0, sequential features): k = 2p, 2p+1 at p = ks*16+(lane>>4)*4+j.
//   L2/L3/L4 (in-register pack): feature at k-position q is
//       pi(q) = (2*(q>>5) + ((q&7)>>2))*16 + ((q>>3)&3)*4 + (q&3).
// bias tiles (per-row): g_bias[bt*256 + lane*4 + r] = b[ot*16 + (lane>>4)*4 + r].
__global__ void prep_weights(const float* __restrict__ W_ih, const float* __restrict__ b_ih,
                             const float* __restrict__ b_hh,
                             const float* __restrict__ W1, const float* __restrict__ b1,
                             const float* __restrict__ W2, const float* __restrict__ b2,
                             const float* __restrict__ W3, const float* __restrict__ b3,
                             const float* __restrict__ W4, const float* __restrict__ b4)
{
    const int gid = blockIdx.x * blockDim.x + threadIdx.x;
    const int gs  = gridDim.x * blockDim.x;

    for (int i = gid; i < N_FRAG_U32; i += gs) {
        int t = i >> 8, rlo = i & 255;
        int lane = rlo >> 2, j = rlo & 3;
        const float* W; int N, K, ld, ks, nt;
        if (t < 8)       { W = W1; N = 51; K = 34; ld = 34; ks = t >> 2;     nt = t & 3; }
        else if (t < 16) { W = W2; N = 51; K = 51; ld = 51; ks = (t-8) >> 2; nt = (t-8) & 3; }
        else if (t < 22) { W = W3; N = 34; K = 51; ld = 51; ks = (t-16) / 3; nt = (t-16) % 3; }
        else             { W = W4; N = 5;  K = 34; ld = 34; ks = t - 22;     nt = 0; }
        int m = nt * 16 + (lane & 15);
        int k_lo, k_hi;
        if (t < 8) {
            int p = ks * 16 + (lane >> 4) * 4 + j;
            k_lo = 2 * p; k_hi = k_lo + 1;
        } else {
            int q = ks * 32 + (lane >> 4) * 8 + 2 * j;
            k_lo = (2 * (q >> 5) + ((q & 7) >> 2)) * 16 + ((q >> 3) & 3) * 4 + (q & 3);
            int q1 = q + 1;
            k_hi = (2 * (q1 >> 5) + ((q1 & 7) >> 2)) * 16 + ((q1 >> 3) & 3) * 4 + (q1 & 3);
        }
        float a = (m < N && k_lo < K) ? W[m * ld + k_lo] : 0.f;
        float b = (m < N && k_hi < K) ? W[m * ld + k_hi] : 0.f;
        g_frag[i] = as_u32(pk(a, b));
    }
    for (int i = gid; i < N_BIAS; i += gs) {
        int bt = i >> 8, rem = i & 255;
        int lane = rem >> 2, r = rem & 3;
        const float* bv; int N, ot;
        if (bt < 4)       { bv = b1; N = 51; ot = bt; }
        else if (bt < 8)  { bv = b2; N = 51; ot = bt - 4; }
        else if (bt < 11) { bv = b3; N = 34; ot = bt - 8; }
        else              { bv = b4; N = 5;  ot = 0; }
        int n = ot * 16 + (lane >> 4) * 4 + r;
        g_bias[i] = (n < N) ? bv[n] : 0.f;
    }
    for (int i = gid; i < N_LSTM; i += gs) {
        int k = i / 24, cc = i - k * 24;
        float v = 0.f;
        if (k < KSEQ) v = (cc < 16) ? W_ih[k * 16 + cc]
                                    : b_ih[k * 8 + (cc - 16)] + b_hh[k * 8 + (cc - 16)];
        g_lstm[i] = v;
    }
}

// ---- main kernel helpers ----
__device__ __forceinline__ h8 load_frag(int tile, int l) {
    union { uint4 u; h8 h; } u;
    u.u = *(const uint4*)&g_frag[tile * 256 + l * 4];
    return u.h;
}

// L1 B-fragments from the stage0 LDS tile (verified read path)
__device__ __forceinline__ void read_bfrags(h8 (&bf)[4][2], const unsigned* my, int l)
{
    const int c = l & 15, g = l >> 4;
    const int mrd = (c & 7) << 2;                        // swizzle mask, row = c
    #pragma unroll
    for (int st = 0; st < 4; ++st)
      #pragma unroll
      for (int ks = 0; ks < 2; ++ks) {
        int idx = (st * 16 + c) * 32 + ((ks * 16 + g * 4) ^ mrd);
        union { uint4 u; h8 h; } u;
        u.u = *(const uint4*)&my[idx];
        bf[st][ks] = u.h;
      }
}

// Swapped-operand layer: acc[ot][st] = W_tile(ot) . act^T(st); ks=0 MFMA
// consumes the per-row bias fragment directly as C.
template<int NT, int TBASE, int BBASE>
__device__ __forceinline__ void layer_swapped(const h8 (&bf)[4][2], f4 (&acc)[4][4], int l)
{
    #pragma unroll
    for (int ot = 0; ot < NT; ++ot) {                    // ks = 0: C = bias(row)
        f4 bias4 = *(const f4*)&g_bias[(BBASE + ot) * 256 + l * 4];
        h8 af = load_frag(TBASE + ot, l);
        #pragma unroll
        for (int st = 0; st < 4; ++st)
          acc[ot][st] = __builtin_amdgcn_mfma_f32_16x16x32_f16(af, bf[st][0], bias4, 0, 0, 0);
    }
    #pragma unroll
    for (int ot = 0; ot < NT; ++ot) {                    // ks = 1: accumulate
        h8 af = load_frag(TBASE + NT + ot, l);
        #pragma unroll
        for (int st = 0; st < 4; ++st)
          acc[ot][st] = __builtin_amdgcn_mfma_f32_16x16x32_f16(af, bf[st][1], acc[ot][st], 0, 0, 0);
    }
}

// In-register relu+pack under the pi k-permutation (pure lane-local)
template<int NT>
__device__ __forceinline__ void pack_bfrags(const f4 (&acc)[4][4], h8 (&bf)[4][2])
{
    #pragma unroll
    for (int st = 0; st < 4; ++st)
      #pragma unroll
      for (int ks = 0; ks < 2; ++ks) {
        const int o0 = 2 * ks, o1 = 2 * ks + 1;
        union { unsigned u[4]; h8 h; } cvt;
        cvt.u[0] = pkrelu(acc[o0][st][0], acc[o0][st][1]);
        cvt.u[1] = pkrelu(acc[o0][st][2], acc[o0][st][3]);
        if (o1 < NT) {
            cvt.u[2] = pkrelu(acc[o1][st][0], acc[o1][st][1]);
            cvt.u[3] = pkrelu(acc[o1][st][2], acc[o1][st][3]);
        } else {
            cvt.u[2] = 0u; cvt.u[3] = 0u;
        }
        bf[st][ks] = cvt.h;
      }
}

// stage0: write full activation row (row = l), sequential pairs, swizzled
__device__ __forceinline__ void stage0(const unsigned (&cp)[32], unsigned* my, int l)
{
    const int m = (l & 7) << 2;
    #pragma unroll
    for (int ch = 0; ch < 8; ++ch) {
        uint4 q = make_uint4(cp[4*ch], cp[4*ch+1], cp[4*ch+2], cp[4*ch+3]);
        *(uint4*)&my[l * 32 + ((4 * ch) ^ m)] = q;
    }
}

__global__ __launch_bounds__(BLK, 4)
void fused_rnn_mlp(const float* __restrict__ in, float* __restrict__ out, int nrows)
{
    __shared__ unsigned act[WPB * 2048];                 // 8 KB per wave-slice
    const int tid = threadIdx.x;
    const int w = tid >> 6, l = tid & 63;
    unsigned* my = &act[w * 2048];
    const long long rb = (long long)blockIdx.x * BLK;
    if (rb + BLK > nrows) return;
    const long long rw = rb + w * 64;

    // own row: 8 x dwordx4 (8B-aligned) + 1 x dwordx2  (9 VMEM vs 17)
    float2 x[17];
    {
        const float* rp = in + (rw + l) * 34;
        #pragma unroll
        for (int q = 0; q < 8; ++q) {
            f4 v = ((const pf4*)(rp))[q].v;
            x[2 * q]     = make_float2(v.x, v.y);
            x[2 * q + 1] = make_float2(v.z, v.w);
        }
        x[16] = *(const float2*)(rp + 32);
    }

    // LSTM heads (scalar-pipe params) -> 11 h-pairs + 6 passthrough pairs
    unsigned cp[32];
    #pragma unroll
    for (int kp = 0; kp < 6; ++kp) {
        u16v c0, c1, c2;
        sload3((const unsigned*)&g_lstm[kp * 48], c0, c1, c2);
        h2 h;
        lstm_one(c0, c1, c2, 0, x[2 * kp], h);
        cp[2 * kp] = as_u32(h);
        if (kp < 5) {
            lstm_one(c0, c1, c2, 24, x[2 * kp + 1], h);
            cp[2 * kp + 1] = as_u32(h);
        }
    }
    #pragma unroll
    for (int t = 0; t < 6; ++t) cp[11 + t] = as_u32(pk(x[11 + t].x, x[11 + t].y));
    #pragma unroll
    for (int t = 17; t < 32; ++t) cp[t] = 0u;            // zero K-tail (NaN-safe)

    stage0(cp, my, l);

    h8 bf[4][2];
    f4 acc[4][4];

    read_bfrags(bf, my, l);                  // L1 B-frags (only LDS round-trip)
    layer_swapped<4, 0, 0>(bf, acc, l);      // L1: 34 -> 51
    pack_bfrags<4>(acc, bf);                 // in-register handoff
    layer_swapped<4, 8, 4>(bf, acc, l);      // L2: 51 -> 51
    pack_bfrags<4>(acc, bf);
    layer_swapped<3, 16, 8>(bf, acc, l);     // L3: 51 -> 34
    pack_bfrags<3>(acc, bf);
    layer_swapped<1, 22, 11>(bf, acc, l);    // L4: 34 -> 5

    // stage PRE-sigmoid f32 (D' transposed: lane holds neurons g*4+r of
    // sample st*16+c) into own (now dead) act region, 9-padded
    {
        const int c = l & 15, g = l >> 4;
        float* po = (float*)my;
        #pragma unroll
        for (int st = 0; st < 4; ++st) {
            const int sample = st * 16 + c;
            #pragma unroll
            for (int r = 0; r < 4; ++r) {
                int n = g * 4 + r;
                if (n < 5) po[sample * 9 + n] = acc[0][st][r];
            }
        }
    }
    // NO __syncthreads: each wave reads back only its OWN region (same-wave
    // LDS RAW is compiler-tracked, as proven by the stage0->read path).

    // per-wave coalesced store: 320 contiguous floats at out + rw*5
    {
        const float* po = (const float*)my;
        const long long ob = rw * 5;
        #pragma unroll
        for (int it = 0; it < 5; ++it) {
            int F   = it * 64 + l;                       // 0..319
            int row = (F * 52429) >> 18;                 // F / 5, exact
            int cc  = F - row * 5;
            out[ob + F] = sig1(po[row * 9 + cc]);
        }
    }
}

extern "C" void kernel_launch(void* const* d_in, const int* in_sizes, int n_in,
                              void* d_out, int out_size, void* d_ws, size_t ws_size,
                              hipStream_t stream)
{
    const float* input = (const float*)d_in[0];
    const float* W_ih  = (const float*)d_in[1];
    const float* b_ih  = (const float*)d_in[2];
    const float* b_hh  = (const float*)d_in[3];
    const float* W1    = (const float*)d_in[4];
    const float* b1    = (const float*)d_in[5];
    const float* W2    = (const float*)d_in[6];
    const float* b2    = (const float*)d_in[7];
    const float* W3    = (const float*)d_in[8];
    const float* b3    = (const float*)d_in[9];
    const float* W4    = (const float*)d_in[10];
    const float* b4    = (const float*)d_in[11];
    float* out = (float*)d_out;

    int nrows = in_sizes[0] / 34;
    int grid  = nrows / BLK;

    hipLaunchKernelGGL(prep_weights, dim3(8), dim3(256), 0, stream,
                       W_ih, b_ih, b_hh, W1, b1, W2, b2, W3, b3, W4, b4);
    hipLaunchKernelGGL(fused_rnn_mlp, dim3(grid), dim3(BLK), 0, stream,
                       input, out, nrows);
}

// Round 20
// 56.405 us; speedup vs baseline: 1.3751x; 1.0141x over previous
//
#include <hip/hip_runtime.h>

// Fused LSTM-heads + 4-layer MLP on the MATRIX pipe — SWAPPED-OPERAND form.
// Each layer computes D' = W · act^T  (A = W, B = activations^T); with the
// pi k-permutation applied to BOTH packed activations and next-layer W
// columns, the inter-layer handoff is PURE IN-REGISTER (8 pkrelu/sample-tile).
// Only L1 reads B-frags from the stage0 LDS tile. Bias rides ks=0 MFMA C.
// r17: input as 8 x dwordx4 + 1 x dwordx2; per-wave barrier-free epilogue.
// r20: LSTM scalar loads PAIRED (sload6: 6 x s_load_dwordx16 behind ONE
//      lgkmcnt(0)) -> 3 serial K$ round-trips instead of 6. Counted lgkm
//      waits are unsafe for SMEM (out-of-order returns), so full waits only.

#define BLK  256
#define WPB  4
#define KSEQ 11

typedef _Float16 h2   __attribute__((ext_vector_type(2)));
typedef _Float16 h8   __attribute__((ext_vector_type(8)));
typedef float    f4   __attribute__((ext_vector_type(4)));
typedef unsigned u16v __attribute__((ext_vector_type(16)));

struct __attribute__((packed, aligned(8))) pf4 { f4 v; };   // align-8 float4 load

#define N_FRAG_U32 6144   // 24 tiles * 64 lanes * 4 u32 (f16 pairs)
#define N_BIAS     3072   // 12 bias-tiles * 64 lanes * 4 rows (f32)
#define N_LSTM     288    // 6 groups * 48 floats (2 k-pairs each)

__device__ __align__(16) float    g_lstm[N_LSTM];
__device__ __align__(16) unsigned g_frag[N_FRAG_U32];
__device__ __align__(16) float    g_bias[N_BIAS];

__device__ __forceinline__ h2 pk(float a, float b) {
    auto r = __builtin_amdgcn_cvt_pkrtz(a, b);
    union { decltype(r) f; h2 h; } c; c.f = r; return c.h;
}
__device__ __forceinline__ unsigned as_u32(h2 h) {
    union { h2 h; unsigned u; } c; c.h = h; return c.u;
}
__device__ __forceinline__ float uf(unsigned u) {
    union { unsigned u; float f; } c; c.u = u; return c.f;
}
__device__ __forceinline__ unsigned pkrelu(float a, float b) {   // pack then v_pk_max_f16
    h2 p = pk(a, b);
    h2 z = {(_Float16)0.0f, (_Float16)0.0f};
    h2 r = __builtin_elementwise_max(p, z);
    return as_u32(r);
}
__device__ __forceinline__ float fast_exp(float x) {
#if __has_builtin(__builtin_amdgcn_exp2f)
    return __builtin_amdgcn_exp2f(x * 1.44269504088896340736f);
#else
    return __expf(x);
#endif
}
__device__ __forceinline__ float fast_rcp(float x) {
#if __has_builtin(__builtin_amdgcn_rcpf)
    return __builtin_amdgcn_rcpf(x);
#else
    return 1.0f / x;
#endif
}
__device__ __forceinline__ float sig1(float x)  { return fast_rcp(1.0f + fast_exp(-x)); }

// sig(a) * tanh(b) with a single rcp
__device__ __forceinline__ float sigtanh(float a, float b) {
    float ea = fast_exp(-a);
    float eb = fast_exp(2.0f * b);
    return (eb - 1.0f) * fast_rcp((1.0f + ea) * (eb + 1.0f));
}

// paired scalar-pipe load: 96 u32 (TWO k-pair groups) behind ONE full wait.
// Consumers depend on asm outputs -> cannot be hoisted above the wait.
__device__ __forceinline__ void sload6(const unsigned* p,
                                       u16v& a0, u16v& a1, u16v& a2,
                                       u16v& b0, u16v& b1, u16v& b2) {
    asm volatile("s_load_dwordx16 %0, %6, 0x0\n\t"
                 "s_load_dwordx16 %1, %6, 0x40\n\t"
                 "s_load_dwordx16 %2, %6, 0x80\n\t"
                 "s_load_dwordx16 %3, %6, 0xc0\n\t"
                 "s_load_dwordx16 %4, %6, 0x100\n\t"
                 "s_load_dwordx16 %5, %6, 0x140\n\t"
                 "s_waitcnt lgkmcnt(0)"
                 : "=&s"(a0), "=&s"(a1), "=&s"(a2),
                   "=&s"(b0), "=&s"(b1), "=&s"(b2) : "s"(p));
}
__device__ __forceinline__ unsigned pick48(const u16v& c0, const u16v& c1, const u16v& c2, int j) {
    return j < 16 ? c0[j] : (j < 32 ? c1[j - 16] : c2[j - 32]);
}

__device__ __forceinline__ void lstm_one(const u16v& c0, const u16v& c1, const u16v& c2, int base,
                                         float2 x, h2& outp)
{
    float w0  = uf(pick48(c0, c1, c2, base + 0)),  float_w1;
    float w1  = uf(pick48(c0, c1, c2, base + 1));
    float w2  = uf(pick48(c0, c1, c2, base + 2)),  w3  = uf(pick48(c0, c1, c2, base + 3));
    float w8  = uf(pick48(c0, c1, c2, base + 8)),  w9  = uf(pick48(c0, c1, c2, base + 9));
    float w10 = uf(pick48(c0, c1, c2, base + 10)), w11 = uf(pick48(c0, c1, c2, base + 11));
    float w12 = uf(pick48(c0, c1, c2, base + 12)), w13 = uf(pick48(c0, c1, c2, base + 13));
    float w14 = uf(pick48(c0, c1, c2, base + 14)), w15 = uf(pick48(c0, c1, c2, base + 15));
    float B0  = uf(pick48(c0, c1, c2, base + 16)), B1v = uf(pick48(c0, c1, c2, base + 17));
    float B4  = uf(pick48(c0, c1, c2, base + 20)), B5  = uf(pick48(c0, c1, c2, base + 21));
    float B6  = uf(pick48(c0, c1, c2, base + 22)), B7  = uf(pick48(c0, c1, c2, base + 23));

    float x0 = x.x, x1 = x.y;
    float gi0 = B0  + x0 * w0  + x1 * w1;
    float gi1 = B1v + x0 * w2  + x1 * w3;
    float gg0 = B4  + x0 * w8  + x1 * w9;
    float gg1 = B5  + x0 * w10 + x1 * w11;
    float go0 = B6  + x0 * w12 + x1 * w13;
    float go1 = B7  + x0 * w14 + x1 * w15;
    float cc0 = sigtanh(gi0, gg0);
    float cc1 = sigtanh(gi1, gg1);
    float h0  = sigtanh(go0, cc0);
    float h1  = sigtanh(go1, cc1);
    outp = pk(h0, h1);
}

// ---- prep: pack W as A-fragments, per-ROW bias tiles, LSTM params ----
// tile ids: L1: 0..7 = ks*4+nt | L2: 8..15 | L3: 16..21 = 16+ks*3+nt | L4: 22..23
// A-frag: lane holds W[m = nt*16+(lane&15)][k-position (lane>>4)*8 + jj of step ks].
//   L1 (stage0, sequential features): k = 2p, 2p+1 at p = ks*16+(lane>>4)*4+j.
//   L2/L3/L4 (in-register pack): feature at k-position q is
//       pi(q) = (2*(q>>5) + ((q&7)>>2))*16 + ((q>>3)&3)*4 + (q&3).
// bias tiles (per-row): g_bias[bt*256 + lane*4 + r] = b[ot*16 + (lane>>4)*4 + r].
__global__ void prep_weights(const float* __restrict__ W_ih, const float* __restrict__ b_ih,
                             const float* __restrict__ b_hh,
                             const float* __restrict__ W1, const float* __restrict__ b1,
                             const float* __restrict__ W2, const float* __restrict__ b2,
                             const float* __restrict__ W3, const float* __restrict__ b3,
                             const float* __restrict__ W4, const float* __restrict__ b4)
{
    const int gid = blockIdx.x * blockDim.x + threadIdx.x;
    const int gs  = gridDim.x * blockDim.x;

    for (int i = gid; i < N_FRAG_U32; i += gs) {
        int t = i >> 8, rlo = i & 255;
        int lane = rlo >> 2, j = rlo & 3;
        const float* W; int N, K, ld, ks, nt;
        if (t < 8)       { W = W1; N = 51; K = 34; ld = 34; ks = t >> 2;     nt = t & 3; }
        else if (t < 16) { W = W2; N = 51; K = 51; ld = 51; ks = (t-8) >> 2; nt = (t-8) & 3; }
        else if (t < 22) { W = W3; N = 34; K = 51; ld = 51; ks = (t-16) / 3; nt = (t-16) % 3; }
        else             { W = W4; N = 5;  K = 34; ld = 34; ks = t - 22;     nt = 0; }
        int m = nt * 16 + (lane & 15);
        int k_lo, k_hi;
        if (t < 8) {
            int p = ks * 16 + (lane >> 4) * 4 + j;
            k_lo = 2 * p; k_hi = k_lo + 1;
        } else {
            int q = ks * 32 + (lane >> 4) * 8 + 2 * j;
            k_lo = (2 * (q >> 5) + ((q & 7) >> 2)) * 16 + ((q >> 3) & 3) * 4 + (q & 3);
            int q1 = q + 1;
            k_hi = (2 * (q1 >> 5) + ((q1 & 7) >> 2)) * 16 + ((q1 >> 3) & 3) * 4 + (q1 & 3);
        }
        float a = (m < N && k_lo < K) ? W[m * ld + k_lo] : 0.f;
        float b = (m < N && k_hi < K) ? W[m * ld + k_hi] : 0.f;
        g_frag[i] = as_u32(pk(a, b));
    }
    for (int i = gid; i < N_BIAS; i += gs) {
        int bt = i >> 8, rem = i & 255;
        int lane = rem >> 2, r = rem & 3;
        const float* bv; int N, ot;
        if (bt < 4)       { bv = b1; N = 51; ot = bt; }
        else if (bt < 8)  { bv = b2; N = 51; ot = bt - 4; }
        else if (bt < 11) { bv = b3; N = 34; ot = bt - 8; }
        else              { bv = b4; N = 5;  ot = 0; }
        int n = ot * 16 + (lane >> 4) * 4 + r;
        g_bias[i] = (n < N) ? bv[n] : 0.f;
    }
    for (int i = gid; i < N_LSTM; i += gs) {
        int k = i / 24, cc = i - k * 24;
        float v = 0.f;
        if (k < KSEQ) v = (cc < 16) ? W_ih[k * 16 + cc]
                                    : b_ih[k * 8 + (cc - 16)] + b_hh[k * 8 + (cc - 16)];
        g_lstm[i] = v;
    }
}

// ---- main kernel helpers ----
__device__ __forceinline__ h8 load_frag(int tile, int l) {
    union { uint4 u; h8 h; } u;
    u.u = *(const uint4*)&g_frag[tile * 256 + l * 4];
    return u.h;
}

// L1 B-fragments from the stage0 LDS tile (verified read path)
__device__ __forceinline__ void read_bfrags(h8 (&bf)[4][2], const unsigned* my, int l)
{
    const int c = l & 15, g = l >> 4;
    const int mrd = (c & 7) << 2;                        // swizzle mask, row = c
    #pragma unroll
    for (int st = 0; st < 4; ++st)
      #pragma unroll
      for (int ks = 0; ks < 2; ++ks) {
        int idx = (st * 16 + c) * 32 + ((ks * 16 + g * 4) ^ mrd);
        union { uint4 u; h8 h; } u;
        u.u = *(const uint4*)&my[idx];
        bf[st][ks] = u.h;
      }
}

// Swapped-operand layer: acc[ot][st] = W_tile(ot) . act^T(st); ks=0 MFMA
// consumes the per-row bias fragment directly as C.
template<int NT, int TBASE, int BBASE>
__device__ __forceinline__ void layer_swapped(const h8 (&bf)[4][2], f4 (&acc)[4][4], int l)
{
    #pragma unroll
    for (int ot = 0; ot < NT; ++ot) {                    // ks = 0: C = bias(row)
        f4 bias4 = *(const f4*)&g_bias[(BBASE + ot) * 256 + l * 4];
        h8 af = load_frag(TBASE + ot, l);
        #pragma unroll
        for (int st = 0; st < 4; ++st)
          acc[ot][st] = __builtin_amdgcn_mfma_f32_16x16x32_f16(af, bf[st][0], bias4, 0, 0, 0);
    }
    #pragma unroll
    for (int ot = 0; ot < NT; ++ot) {                    // ks = 1: accumulate
        h8 af = load_frag(TBASE + NT + ot, l);
        #pragma unroll
        for (int st = 0; st < 4; ++st)
          acc[ot][st] = __builtin_amdgcn_mfma_f32_16x16x32_f16(af, bf[st][1], acc[ot][st], 0, 0, 0);
    }
}

// In-register relu+pack under the pi k-permutation (pure lane-local)
template<int NT>
__device__ __forceinline__ void pack_bfrags(const f4 (&acc)[4][4], h8 (&bf)[4][2])
{
    #pragma unroll
    for (int st = 0; st < 4; ++st)
      #pragma unroll
      for (int ks = 0; ks < 2; ++ks) {
        const int o0 = 2 * ks, o1 = 2 * ks + 1;
        union { unsigned u[4]; h8 h; } cvt;
        cvt.u[0] = pkrelu(acc[o0][st][0], acc[o0][st][1]);
        cvt.u[1] = pkrelu(acc[o0][st][2], acc[o0][st][3]);
        if (o1 < NT) {
            cvt.u[2] = pkrelu(acc[o1][st][0], acc[o1][st][1]);
            cvt.u[3] = pkrelu(acc[o1][st][2], acc[o1][st][3]);
        } else {
            cvt.u[2] = 0u; cvt.u[3] = 0u;
        }
        bf[st][ks] = cvt.h;
      }
}

// stage0: write full activation row (row = l), sequential pairs, swizzled
__device__ __forceinline__ void stage0(const unsigned (&cp)[32], unsigned* my, int l)
{
    const int m = (l & 7) << 2;
    #pragma unroll
    for (int ch = 0; ch < 8; ++ch) {
        uint4 q = make_uint4(cp[4*ch], cp[4*ch+1], cp[4*ch+2], cp[4*ch+3]);
        *(uint4*)&my[l * 32 + ((4 * ch) ^ m)] = q;
    }
}

__global__ __launch_bounds__(BLK, 3)
void fused_rnn_mlp(const float* __restrict__ in, float* __restrict__ out, int nrows)
{
    __shared__ unsigned act[WPB * 2048];                 // 8 KB per wave-slice
    const int tid = threadIdx.x;
    const int w = tid >> 6, l = tid & 63;
    unsigned* my = &act[w * 2048];
    const long long rb = (long long)blockIdx.x * BLK;
    if (rb + BLK > nrows) return;
    const long long rw = rb + w * 64;

    // own row: 8 x dwordx4 (8B-aligned) + 1 x dwordx2  (9 VMEM vs 17)
    float2 x[17];
    {
        const float* rp = in + (rw + l) * 34;
        #pragma unroll
        for (int q = 0; q < 8; ++q) {
            f4 v = ((const pf4*)(rp))[q].v;
            x[2 * q]     = make_float2(v.x, v.y);
            x[2 * q + 1] = make_float2(v.z, v.w);
        }
        x[16] = *(const float2*)(rp + 32);
    }

    // LSTM heads: PAIRED scalar loads (2 k-pairs per wait) -> 3 serial waits
    unsigned cp[32];
    #pragma unroll
    for (int gp = 0; gp < 3; ++gp) {
        u16v a0, a1, a2, b0, b1, b2;
        sload6((const unsigned*)&g_lstm[gp * 96], a0, a1, a2, b0, b1, b2);
        const int kp = 2 * gp;
        h2 h;
        lstm_one(a0, a1, a2, 0,  x[2 * kp],     h); cp[2 * kp]     = as_u32(h);
        lstm_one(a0, a1, a2, 24, x[2 * kp + 1], h); cp[2 * kp + 1] = as_u32(h);
        lstm_one(b0, b1, b2, 0,  x[2 * kp + 2], h); cp[2 * kp + 2] = as_u32(h);
        if (gp < 2) {
            lstm_one(b0, b1, b2, 24, x[2 * kp + 3], h); cp[2 * kp + 3] = as_u32(h);
        }
    }
    #pragma unroll
    for (int t = 0; t < 6; ++t) cp[11 + t] = as_u32(pk(x[11 + t].x, x[11 + t].y));
    #pragma unroll
    for (int t = 17; t < 32; ++t) cp[t] = 0u;            // zero K-tail (NaN-safe)

    stage0(cp, my, l);

    h8 bf[4][2];
    f4 acc[4][4];

    read_bfrags(bf, my, l);                  // L1 B-frags (only LDS round-trip)
    layer_swapped<4, 0, 0>(bf, acc, l);      // L1: 34 -> 51
    pack_bfrags<4>(acc, bf);                 // in-register handoff
    layer_swapped<4, 8, 4>(bf, acc, l);      // L2: 51 -> 51
    pack_bfrags<4>(acc, bf);
    layer_swapped<3, 16, 8>(bf, acc, l);     // L3: 51 -> 34
    pack_bfrags<3>(acc, bf);
    layer_swapped<1, 22, 11>(bf, acc, l);    // L4: 34 -> 5

    // stage PRE-sigmoid f32 (D' transposed: lane holds neurons g*4+r of
    // sample st*16+c) into own (now dead) act region, 9-padded
    {
        const int c = l & 15, g = l >> 4;
        float* po = (float*)my;
        #pragma unroll
        for (int st = 0; st < 4; ++st) {
            const int sample = st * 16 + c;
            #pragma unroll
            for (int r = 0; r < 4; ++r) {
                int n = g * 4 + r;
                if (n < 5) po[sample * 9 + n] = acc[0][st][r];
            }
        }
    }
    // NO __syncthreads: each wave reads back only its OWN region (same-wave
    // LDS RAW is compiler-tracked, as proven by the stage0->read path).

    // per-wave coalesced store: 320 contiguous floats at out + rw*5
    {
        const float* po = (const float*)my;
        const long long ob = rw * 5;
        #pragma unroll
        for (int it = 0; it < 5; ++it) {
            int F   = it * 64 + l;                       // 0..319
            int row = (F * 52429) >> 18;                 // F / 5, exact
            int cc  = F - row * 5;
            out[ob + F] = sig1(po[row * 9 + cc]);
        }
    }
}

extern "C" void kernel_launch(void* const* d_in, const int* in_sizes, int n_in,
                              void* d_out, int out_size, void* d_ws, size_t ws_size,
                              hipStream_t stream)
{
    const float* input = (const float*)d_in[0];
    const float* W_ih  = (const float*)d_in[1];
    const float* b_ih  = (const float*)d_in[2];
    const float* b_hh  = (const float*)d_in[3];
    const float* W1    = (const float*)d_in[4];
    const float* b1    = (const float*)d_in[5];
    const float* W2    = (const float*)d_in[6];
    const float* b2    = (const float*)d_in[7];
    const float* W3    = (const float*)d_in[8];
    const float* b3    = (const float*)d_in[9];
    const float* W4    = (const float*)d_in[10];
    const float* b4    = (const float*)d_in[11];
    float* out = (float*)d_out;

    int nrows = in_sizes[0] / 34;
    int grid  = nrows / BLK;

    hipLaunchKernelGGL(prep_weights, dim3(8), dim3(256), 0, stream,
                       W_ih, b_ih, b_hh, W1, b1, W2, b2, W3, b3, W4, b4);
    hipLaunchKernelGGL(fused_rnn_mlp, dim3(grid), dim3(BLK), 0, stream,
                       input, out, nrows);
}

// Round 21
// 53.106 us; speedup vs baseline: 1.4606x; 1.0621x over previous
//
#include <hip/hip_runtime.h>

// Fused LSTM-heads + 4-layer MLP on the MATRIX pipe — SWAPPED-OPERAND form.
// Each layer computes D' = W · act^T  (A = W, B = activations^T); with the
// pi k-permutation applied to BOTH packed activations and next-layer W
// columns, the inter-layer handoff is PURE IN-REGISTER (8 pkrelu/sample-tile).
// Only L1 reads B-frags from the stage0 LDS tile. Bias rides ks=0 MFMA C.
// r17 FINAL (empirical optimum, 52.94 us): input as 8 x dwordx4 + 1 x
// dwordx2; per-wave barrier-free epilogue; launch_bounds(256,3).
// Reverted r18/r19/r20 experiments (all regressions).

#define BLK  256
#define WPB  4
#define KSEQ 11

typedef _Float16 h2   __attribute__((ext_vector_type(2)));
typedef _Float16 h8   __attribute__((ext_vector_type(8)));
typedef float    f4   __attribute__((ext_vector_type(4)));
typedef unsigned u16v __attribute__((ext_vector_type(16)));

struct __attribute__((packed, aligned(8))) pf4 { f4 v; };   // align-8 float4 load

#define N_FRAG_U32 6144   // 24 tiles * 64 lanes * 4 u32 (f16 pairs)
#define N_BIAS     3072   // 12 bias-tiles * 64 lanes * 4 rows (f32)
#define N_LSTM     288    // 12 * 24 floats (W_ih 16 + folded bias 8 per k)

__device__ __align__(16) float    g_lstm[N_LSTM];
__device__ __align__(16) unsigned g_frag[N_FRAG_U32];
__device__ __align__(16) float    g_bias[N_BIAS];

__device__ __forceinline__ h2 pk(float a, float b) {
    auto r = __builtin_amdgcn_cvt_pkrtz(a, b);
    union { decltype(r) f; h2 h; } c; c.f = r; return c.h;
}
__device__ __forceinline__ unsigned as_u32(h2 h) {
    union { h2 h; unsigned u; } c; c.h = h; return c.u;
}
__device__ __forceinline__ float uf(unsigned u) {
    union { unsigned u; float f; } c; c.u = u; return c.f;
}
__device__ __forceinline__ unsigned pkrelu(float a, float b) {   // pack then v_pk_max_f16
    h2 p = pk(a, b);
    h2 z = {(_Float16)0.0f, (_Float16)0.0f};
    h2 r = __builtin_elementwise_max(p, z);
    return as_u32(r);
}
__device__ __forceinline__ float fast_exp(float x) {
#if __has_builtin(__builtin_amdgcn_exp2f)
    return __builtin_amdgcn_exp2f(x * 1.44269504088896340736f);
#else
    return __expf(x);
#endif
}
__device__ __forceinline__ float fast_rcp(float x) {
#if __has_builtin(__builtin_amdgcn_rcpf)
    return __builtin_amdgcn_rcpf(x);
#else
    return 1.0f / x;
#endif
}
__device__ __forceinline__ float sig1(float x)  { return fast_rcp(1.0f + fast_exp(-x)); }

// sig(a) * tanh(b) with a single rcp
__device__ __forceinline__ float sigtanh(float a, float b) {
    float ea = fast_exp(-a);
    float eb = fast_exp(2.0f * b);
    return (eb - 1.0f) * fast_rcp((1.0f + ea) * (eb + 1.0f));
}

// scalar-pipe load of 48 u32 (LSTM params for a k-pair); waitcnt fused in-block
__device__ __forceinline__ void sload3(const unsigned* p, u16v& c0, u16v& c1, u16v& c2) {
    asm volatile("s_load_dwordx16 %0, %3, 0x0\n\t"
                 "s_load_dwordx16 %1, %3, 0x40\n\t"
                 "s_load_dwordx16 %2, %3, 0x80\n\t"
                 "s_waitcnt lgkmcnt(0)"
                 : "=&s"(c0), "=&s"(c1), "=&s"(c2) : "s"(p));
}
__device__ __forceinline__ unsigned pick48(const u16v& c0, const u16v& c1, const u16v& c2, int j) {
    return j < 16 ? c0[j] : (j < 32 ? c1[j - 16] : c2[j - 32]);
}

__device__ __forceinline__ void lstm_one(const u16v& c0, const u16v& c1, const u16v& c2, int base,
                                         float2 x, h2& outp)
{
    float w0  = uf(pick48(c0, c1, c2, base + 0)),  w1  = uf(pick48(c0, c1, c2, base + 1));
    float w2  = uf(pick48(c0, c1, c2, base + 2)),  w3  = uf(pick48(c0, c1, c2, base + 3));
    float w8  = uf(pick48(c0, c1, c2, base + 8)),  w9  = uf(pick48(c0, c1, c2, base + 9));
    float w10 = uf(pick48(c0, c1, c2, base + 10)), w11 = uf(pick48(c0, c1, c2, base + 11));
    float w12 = uf(pick48(c0, c1, c2, base + 12)), w13 = uf(pick48(c0, c1, c2, base + 13));
    float w14 = uf(pick48(c0, c1, c2, base + 14)), w15 = uf(pick48(c0, c1, c2, base + 15));
    float B0  = uf(pick48(c0, c1, c2, base + 16)), B1v = uf(pick48(c0, c1, c2, base + 17));
    float B4  = uf(pick48(c0, c1, c2, base + 20)), B5  = uf(pick48(c0, c1, c2, base + 21));
    float B6  = uf(pick48(c0, c1, c2, base + 22)), B7  = uf(pick48(c0, c1, c2, base + 23));

    float x0 = x.x, x1 = x.y;
    float gi0 = B0  + x0 * w0  + x1 * w1;
    float gi1 = B1v + x0 * w2  + x1 * w3;
    float gg0 = B4  + x0 * w8  + x1 * w9;
    float gg1 = B5  + x0 * w10 + x1 * w11;
    float go0 = B6  + x0 * w12 + x1 * w13;
    float go1 = B7  + x0 * w14 + x1 * w15;
    float cc0 = sigtanh(gi0, gg0);
    float cc1 = sigtanh(gi1, gg1);
    float h0  = sigtanh(go0, cc0);
    float h1  = sigtanh(go1, cc1);
    outp = pk(h0, h1);
}

// ---- prep: pack W as A-fragments, per-ROW bias tiles, LSTM params ----
// tile ids: L1: 0..7 = ks*4+nt | L2: 8..15 | L3: 16..21 = 16+ks*3+nt | L4: 22..23
// A-frag: lane holds W[m = nt*16+(lane&15)][k-position (lane>>4)*8 + jj of step ks].
//   L1 (stage0, sequential features): k = 2p, 2p+1 at p = ks*16+(lane>>4)*4+j.
//   L2/L3/L4 (in-register pack): feature at k-position q is
//       pi(q) = (2*(q>>5) + ((q&7)>>2))*16 + ((q>>3)&3)*4 + (q&3).
// bias tiles (per-row): g_bias[bt*256 + lane*4 + r] = b[ot*16 + (lane>>4)*4 + r].
__global__ void prep_weights(const float* __restrict__ W_ih, const float* __restrict__ b_ih,
                             const float* __restrict__ b_hh,
                             const float* __restrict__ W1, const float* __restrict__ b1,
                             const float* __restrict__ W2, const float* __restrict__ b2,
                             const float* __restrict__ W3, const float* __restrict__ b3,
                             const float* __restrict__ W4, const float* __restrict__ b4)
{
    const int gid = blockIdx.x * blockDim.x + threadIdx.x;
    const int gs  = gridDim.x * blockDim.x;

    for (int i = gid; i < N_FRAG_U32; i += gs) {
        int t = i >> 8, rlo = i & 255;
        int lane = rlo >> 2, j = rlo & 3;
        const float* W; int N, K, ld, ks, nt;
        if (t < 8)       { W = W1; N = 51; K = 34; ld = 34; ks = t >> 2;     nt = t & 3; }
        else if (t < 16) { W = W2; N = 51; K = 51; ld = 51; ks = (t-8) >> 2; nt = (t-8) & 3; }
        else if (t < 22) { W = W3; N = 34; K = 51; ld = 51; ks = (t-16) / 3; nt = (t-16) % 3; }
        else             { W = W4; N = 5;  K = 34; ld = 34; ks = t - 22;     nt = 0; }
        int m = nt * 16 + (lane & 15);
        int k_lo, k_hi;
        if (t < 8) {
            int p = ks * 16 + (lane >> 4) * 4 + j;
            k_lo = 2 * p; k_hi = k_lo + 1;
        } else {
            int q = ks * 32 + (lane >> 4) * 8 + 2 * j;
            k_lo = (2 * (q >> 5) + ((q & 7) >> 2)) * 16 + ((q >> 3) & 3) * 4 + (q & 3);
            int q1 = q + 1;
            k_hi = (2 * (q1 >> 5) + ((q1 & 7) >> 2)) * 16 + ((q1 >> 3) & 3) * 4 + (q1 & 3);
        }
        float a = (m < N && k_lo < K) ? W[m * ld + k_lo] : 0.f;
        float b = (m < N && k_hi < K) ? W[m * ld + k_hi] : 0.f;
        g_frag[i] = as_u32(pk(a, b));
    }
    for (int i = gid; i < N_BIAS; i += gs) {
        int bt = i >> 8, rem = i & 255;
        int lane = rem >> 2, r = rem & 3;
        const float* bv; int N, ot;
        if (bt < 4)       { bv = b1; N = 51; ot = bt; }
        else if (bt < 8)  { bv = b2; N = 51; ot = bt - 4; }
        else if (bt < 11) { bv = b3; N = 34; ot = bt - 8; }
        else              { bv = b4; N = 5;  ot = 0; }
        int n = ot * 16 + (lane >> 4) * 4 + r;
        g_bias[i] = (n < N) ? bv[n] : 0.f;
    }
    for (int i = gid; i < N_LSTM; i += gs) {
        int k = i / 24, cc = i - k * 24;
        float v = 0.f;
        if (k < KSEQ) v = (cc < 16) ? W_ih[k * 16 + cc]
                                    : b_ih[k * 8 + (cc - 16)] + b_hh[k * 8 + (cc - 16)];
        g_lstm[i] = v;
    }
}

// ---- main kernel helpers ----
__device__ __forceinline__ h8 load_frag(int tile, int l) {
    union { uint4 u; h8 h; } u;
    u.u = *(const uint4*)&g_frag[tile * 256 + l * 4];
    return u.h;
}

// L1 B-fragments from the stage0 LDS tile (verified read path)
__device__ __forceinline__ void read_bfrags(h8 (&bf)[4][2], const unsigned* my, int l)
{
    const int c = l & 15, g = l >> 4;
    const int mrd = (c & 7) << 2;                        // swizzle mask, row = c
    #pragma unroll
    for (int st = 0; st < 4; ++st)
      #pragma unroll
      for (int ks = 0; ks < 2; ++ks) {
        int idx = (st * 16 + c) * 32 + ((ks * 16 + g * 4) ^ mrd);
        union { uint4 u; h8 h; } u;
        u.u = *(const uint4*)&my[idx];
        bf[st][ks] = u.h;
      }
}

// Swapped-operand layer: acc[ot][st] = W_tile(ot) . act^T(st); ks=0 MFMA
// consumes the per-row bias fragment directly as C.
template<int NT, int TBASE, int BBASE>
__device__ __forceinline__ void layer_swapped(const h8 (&bf)[4][2], f4 (&acc)[4][4], int l)
{
    #pragma unroll
    for (int ot = 0; ot < NT; ++ot) {                    // ks = 0: C = bias(row)
        f4 bias4 = *(const f4*)&g_bias[(BBASE + ot) * 256 + l * 4];
        h8 af = load_frag(TBASE + ot, l);
        #pragma unroll
        for (int st = 0; st < 4; ++st)
          acc[ot][st] = __builtin_amdgcn_mfma_f32_16x16x32_f16(af, bf[st][0], bias4, 0, 0, 0);
    }
    #pragma unroll
    for (int ot = 0; ot < NT; ++ot) {                    // ks = 1: accumulate
        h8 af = load_frag(TBASE + NT + ot, l);
        #pragma unroll
        for (int st = 0; st < 4; ++st)
          acc[ot][st] = __builtin_amdgcn_mfma_f32_16x16x32_f16(af, bf[st][1], acc[ot][st], 0, 0, 0);
    }
}

// In-register relu+pack under the pi k-permutation (pure lane-local)
template<int NT>
__device__ __forceinline__ void pack_bfrags(const f4 (&acc)[4][4], h8 (&bf)[4][2])
{
    #pragma unroll
    for (int st = 0; st < 4; ++st)
      #pragma unroll
      for (int ks = 0; ks < 2; ++ks) {
        const int o0 = 2 * ks, o1 = 2 * ks + 1;
        union { unsigned u[4]; h8 h; } cvt;
        cvt.u[0] = pkrelu(acc[o0][st][0], acc[o0][st][1]);
        cvt.u[1] = pkrelu(acc[o0][st][2], acc[o0][st][3]);
        if (o1 < NT) {
            cvt.u[2] = pkrelu(acc[o1][st][0], acc[o1][st][1]);
            cvt.u[3] = pkrelu(acc[o1][st][2], acc[o1][st][3]);
        } else {
            cvt.u[2] = 0u; cvt.u[3] = 0u;
        }
        bf[st][ks] = cvt.h;
      }
}

// stage0: write full activation row (row = l), sequential pairs, swizzled
__device__ __forceinline__ void stage0(const unsigned (&cp)[32], unsigned* my, int l)
{
    const int m = (l & 7) << 2;
    #pragma unroll
    for (int ch = 0; ch < 8; ++ch) {
        uint4 q = make_uint4(cp[4*ch], cp[4*ch+1], cp[4*ch+2], cp[4*ch+3]);
        *(uint4*)&my[l * 32 + ((4 * ch) ^ m)] = q;
    }
}

__global__ __launch_bounds__(BLK, 3)
void fused_rnn_mlp(const float* __restrict__ in, float* __restrict__ out, int nrows)
{
    __shared__ unsigned act[WPB * 2048];                 // 8 KB per wave-slice
    const int tid = threadIdx.x;
    const int w = tid >> 6, l = tid & 63;
    unsigned* my = &act[w * 2048];
    const long long rb = (long long)blockIdx.x * BLK;
    if (rb + BLK > nrows) return;
    const long long rw = rb + w * 64;

    // own row: 8 x dwordx4 (8B-aligned) + 1 x dwordx2  (9 VMEM vs 17)
    float2 x[17];
    {
        const float* rp = in + (rw + l) * 34;
        #pragma unroll
        for (int q = 0; q < 8; ++q) {
            f4 v = ((const pf4*)(rp))[q].v;
            x[2 * q]     = make_float2(v.x, v.y);
            x[2 * q + 1] = make_float2(v.z, v.w);
        }
        x[16] = *(const float2*)(rp + 32);
    }

    // LSTM heads (scalar-pipe params) -> 11 h-pairs + 6 passthrough pairs
    unsigned cp[32];
    #pragma unroll
    for (int kp = 0; kp < 6; ++kp) {
        u16v c0, c1, c2;
        sload3((const unsigned*)&g_lstm[kp * 48], c0, c1, c2);
        h2 h;
        lstm_one(c0, c1, c2, 0, x[2 * kp], h);
        cp[2 * kp] = as_u32(h);
        if (kp < 5) {
            lstm_one(c0, c1, c2, 24, x[2 * kp + 1], h);
            cp[2 * kp + 1] = as_u32(h);
        }
    }
    #pragma unroll
    for (int t = 0; t < 6; ++t) cp[11 + t] = as_u32(pk(x[11 + t].x, x[11 + t].y));
    #pragma unroll
    for (int t = 17; t < 32; ++t) cp[t] = 0u;            // zero K-tail (NaN-safe)

    stage0(cp, my, l);

    h8 bf[4][2];
    f4 acc[4][4];

    read_bfrags(bf, my, l);                  // L1 B-frags (only LDS round-trip)
    layer_swapped<4, 0, 0>(bf, acc, l);      // L1: 34 -> 51
    pack_bfrags<4>(acc, bf);                 // in-register handoff
    layer_swapped<4, 8, 4>(bf, acc, l);      // L2: 51 -> 51
    pack_bfrags<4>(acc, bf);
    layer_swapped<3, 16, 8>(bf, acc, l);     // L3: 51 -> 34
    pack_bfrags<3>(acc, bf);
    layer_swapped<1, 22, 11>(bf, acc, l);    // L4: 34 -> 5

    // stage PRE-sigmoid f32 (D' transposed: lane holds neurons g*4+r of
    // sample st*16+c) into own (now dead) act region, 9-padded
    {
        const int c = l & 15, g = l >> 4;
        float* po = (float*)my;
        #pragma unroll
        for (int st = 0; st < 4; ++st) {
            const int sample = st * 16 + c;
            #pragma unroll
            for (int r = 0; r < 4; ++r) {
                int n = g * 4 + r;
                if (n < 5) po[sample * 9 + n] = acc[0][st][r];
            }
        }
    }
    // NO __syncthreads: each wave reads back only its OWN region (same-wave
    // LDS RAW is compiler-tracked, as proven by the stage0->read path).

    // per-wave coalesced store: 320 contiguous floats at out + rw*5
    {
        const float* po = (const float*)my;
        const long long ob = rw * 5;
        #pragma unroll
        for (int it = 0; it < 5; ++it) {
            int F   = it * 64 + l;                       // 0..319
            int row = (F * 52429) >> 18;                 // F / 5, exact
            int cc  = F - row * 5;
            out[ob + F] = sig1(po[row * 9 + cc]);
        }
    }
}

extern "C" void kernel_launch(void* const* d_in, const int* in_sizes, int n_in,
                              void* d_out, int out_size, void* d_ws, size_t ws_size,
                              hipStream_t stream)
{
    const float* input = (const float*)d_in[0];
    const float* W_ih  = (const float*)d_in[1];
    const float* b_ih  = (const float*)d_in[2];
    const float* b_hh  = (const float*)d_in[3];
    const float* W1    = (const float*)d_in[4];
    const float* b1    = (const float*)d_in[5];
    const float* W2    = (const float*)d_in[6];
    const float* b2    = (const float*)d_in[7];
    const float* W3    = (const float*)d_in[8];
    const float* b3    = (const float*)d_in[9];
    const float* W4    = (const float*)d_in[10];
    const float* b4    = (const float*)d_in[11];
    float* out = (float*)d_out;

    int nrows = in_sizes[0] / 34;
    int grid  = nrows / BLK;

    hipLaunchKernelGGL(prep_weights, dim3(8), dim3(256), 0, stream,
                       W_ih, b_ih, b_hh, W1, b1, W2, b2, W3, b3, W4, b4);
    hipLaunchKernelGGL(fused_rnn_mlp, dim3(grid), dim3(BLK), 0, stream,
                       input, out, nrows);
}